// Round 16
// baseline (343.533 us; speedup 1.0000x reference)
//
#include <hip/hip_runtime.h>
#include <cmath>

typedef __attribute__((ext_vector_type(8))) _Float16 half8;
typedef __attribute__((ext_vector_type(4))) _Float16 half4;
typedef __attribute__((ext_vector_type(4))) float f32x4;

__device__ __forceinline__ void glds16(const void* g, void* l) {
  __builtin_amdgcn_global_load_lds(
      (__attribute__((address_space(1))) const void*)g,
      (__attribute__((address_space(3))) void*)l, 16, 0, 0);
}

// A&S 7.1.26, |err| <= 1.5e-7
__device__ __forceinline__ float fast_erf(float x) {
  float ax = fabsf(x);
  float t = 1.0f / (1.0f + 0.3275911f * ax);
  float y = t * (0.254829592f +
            t * (-0.284496736f +
            t * (1.421413741f +
            t * (-1.453152027f + t * 1.061405429f))));
  float r = 1.0f - y * __expf(-ax * ax);
  return copysignf(r, x);
}

// ======== fused prep: x cvt (4096 blk) + 6 weight transposes (3072 blk) + biascat (12 blk) ========
__global__ __launch_bounds__(256) void k_prep(
    const float* __restrict__ x, _Float16* __restrict__ xb,
    const float* __restrict__ Wq, const float* __restrict__ Wk,
    const float* __restrict__ Wv, const float* __restrict__ Wo,
    const float* __restrict__ W1, const float* __restrict__ W2,
    _Float16* __restrict__ Wqkvt, _Float16* __restrict__ Wot,
    _Float16* __restrict__ W1t, _Float16* __restrict__ W2t,
    const float* __restrict__ bq, const float* __restrict__ bk,
    const float* __restrict__ bv, float* __restrict__ bqkv) {
  __shared__ float t[64][65];
  const int tid = threadIdx.x;
  const int bid = blockIdx.x;
  if (bid < 4096) {  // x f32 -> f16
    int i = (bid * 256 + tid) * 8;
    const f32x4* p = (const f32x4*)(x + i);
    f32x4 a = p[0], b = p[1];
    half8 h;
    h[0] = (_Float16)a[0]; h[1] = (_Float16)a[1]; h[2] = (_Float16)a[2]; h[3] = (_Float16)a[3];
    h[4] = (_Float16)b[0]; h[5] = (_Float16)b[1]; h[6] = (_Float16)b[2]; h[7] = (_Float16)b[3];
    *(half8*)(xb + i) = h;
    return;
  }
  const int tt = bid - 4096;
  if (tt >= 3072) {  // biascat (12 blocks)
    int i = (tt - 3072) * 256 + tid;
    const float* s = i < 1024 ? bq : (i < 2048 ? bk : bv);
    bqkv[i] = s[i & 1023];
    return;
  }
  // weight transpose: W [K,N] f32 -> Wt [N,K] f16, 64x64 tile
  const float* W; _Float16* Wt; int K, N, bx, by;
  if (tt < 1024) {
    const int wsel = tt >> 8, r = tt & 255;
    W = wsel == 0 ? Wq : wsel == 1 ? Wk : wsel == 2 ? Wv : Wo;
    Wt = wsel < 3 ? Wqkvt + (size_t)wsel * 1024 * 1024 : Wot;
    K = 1024; N = 1024; bx = r & 15; by = r >> 4;
  } else if (tt < 2048) {
    const int r = tt - 1024;
    W = W1; Wt = W1t; K = 1024; N = 4096; bx = r & 63; by = r >> 6;
  } else {
    const int r = tt - 2048;
    W = W2; Wt = W2t; K = 4096; N = 1024; bx = r & 15; by = r >> 4;
  }
  const int k0 = by << 6, n0 = bx << 6;
  {
    const int r = tid >> 2, q = tid & 3;
    const float* src = &W[(size_t)(k0 + r) * N + n0 + q * 16];
    f32x4 v0 = *(const f32x4*)(src);
    f32x4 v1 = *(const f32x4*)(src + 4);
    f32x4 v2 = *(const f32x4*)(src + 8);
    f32x4 v3 = *(const f32x4*)(src + 12);
    float* d = &t[r][q * 16];
#pragma unroll
    for (int j = 0; j < 4; ++j) d[j] = v0[j];
#pragma unroll
    for (int j = 0; j < 4; ++j) d[4 + j] = v1[j];
#pragma unroll
    for (int j = 0; j < 4; ++j) d[8 + j] = v2[j];
#pragma unroll
    for (int j = 0; j < 4; ++j) d[12 + j] = v3[j];
  }
  __syncthreads();
#pragma unroll
  for (int p = 0; p < 2; ++p) {
    const int c = p * 256 + tid;
    const int row = c >> 3, c8 = c & 7;
    half8 hv;
#pragma unroll
    for (int j = 0; j < 8; ++j) hv[j] = (_Float16)t[c8 * 8 + j][row];
    *(half8*)&Wt[(size_t)(n0 + row) * K + k0 + c8 * 8] = hv;
  }
}

// ======== quadrant 8-phase GEMM: BM=256,BN=256, BK=64, dbuf, DEEP spread staging ========
template <int BM, int EPI>
__global__ __launch_bounds__(512, 2) void k_gemm8(
    const _Float16* __restrict__ A, const _Float16* __restrict__ Bt,
    const float* __restrict__ bias, const float* __restrict__ res,
    float* __restrict__ outf, _Float16* __restrict__ outh, int M, int N, int K) {
  constexpr int MR = BM / 32;
  constexpr int MH2 = MR / 2;
  constexpr int AL = BM * 64;
  constexpr int BL = 256 * 64;
  constexpr int ABYTES = BM * 128;
  constexpr int BBYTES = 256 * 128;
  constexpr int AB2 = 2 * ABYTES;
  __shared__ _Float16 lds[2 * (AL + BL)];
  const char* ldsc = (const char*)lds;

  const int tid = threadIdx.x;
  const int lane = tid & 63;
  const int w = tid >> 6, wr = w >> 2, wc = w & 3;
  const int l15 = lane & 15, grp = lane >> 4;

  const int gx = gridDim.x;
  const int nwg = gx * gridDim.y;
  const int lid = blockIdx.y * gx + blockIdx.x;
  const int wid = (lid & 7) * (nwg >> 3) + (lid >> 3);
  const int m0 = (wid / gx) * BM, n0 = (wid % gx) * 256;

  const int m2 = (l15 >> 2) & 1, m01 = l15 & 3;
  const int chunk0 = (m2 << 2) | (grp ^ m01);
  const int aoff0 = wr * 2048 + l15 * 128 + chunk0 * 16;
  const int aoff1 = aoff0 ^ 64;
  const int boff0 = wc * 2048 + l15 * 128 + chunk0 * 16;
  const int boff1 = boff0 ^ 64;

  const int srow = tid >> 3;
  const int scs8 = ((tid & 7) ^ (srow & 7)) * 8;
  const int NK = K >> 6;

  f32x4 acc[MR][4] = {};
  half8 af[MH2][2], bf[2][2];

#define STG_A(J, MHH, KN)                                                      \
  _Pragma("unroll") for (int s = 0; s < BM / 128; ++s)                         \
      glds16(A + (size_t)(m0 + (MHH) * (BM / 2) + s * 64 + srow) * K +         \
                 (size_t)(KN)*64 + scs8,                                       \
             lds + (J)*AL + ((MHH) * (BM / 2) + s * 64) * 64 + tid * 8);
#define STG_B(J, NHH, KN)                                                      \
  _Pragma("unroll") for (int s = 0; s < 2; ++s)                                \
      glds16(Bt + (size_t)(n0 + (NHH)*128 + s * 64 + srow) * K +               \
                  (size_t)(KN)*64 + scs8,                                      \
             lds + 2 * AL + (J)*BL + ((NHH)*128 + s * 64) * 64 + tid * 8);

#define VM_8 asm volatile("s_waitcnt vmcnt(8)" ::: "memory")
#define VM_6 asm volatile("s_waitcnt vmcnt(6)" ::: "memory")
#define VM_NONE

#define PHASE(J, MHQ, NHQ, RA, RB, STGSTMT, VMSTMT)                            \
  {                                                                            \
    if constexpr (RA) {                                                        \
      _Pragma("unroll") for (int i = 0; i < MH2; ++i) {                        \
        af[i][0] = *(const half8*)(ldsc + (J)*ABYTES +                         \
                                   ((MHQ)*MH2 + i) * 4096 + aoff0);            \
        af[i][1] = *(const half8*)(ldsc + (J)*ABYTES +                         \
                                   ((MHQ)*MH2 + i) * 4096 + aoff1);            \
      }                                                                        \
    }                                                                          \
    if constexpr (RB) {                                                        \
      _Pragma("unroll") for (int n = 0; n < 2; ++n) {                          \
        bf[n][0] = *(const half8*)(ldsc + AB2 + (J)*BBYTES +                   \
                                   ((NHQ)*2 + n) * 8192 + boff0);              \
        bf[n][1] = *(const half8*)(ldsc + AB2 + (J)*BBYTES +                   \
                                   ((NHQ)*2 + n) * 8192 + boff1);              \
      }                                                                        \
    }                                                                          \
    STGSTMT;                                                                   \
    __builtin_amdgcn_s_barrier();                                              \
    asm volatile("s_waitcnt lgkmcnt(0)");                                      \
    __builtin_amdgcn_sched_barrier(0);                                         \
    __builtin_amdgcn_s_setprio(1);                                             \
    _Pragma("unroll") for (int ks = 0; ks < 2; ++ks)                           \
        _Pragma("unroll") for (int i = 0; i < MH2; ++i)                        \
            _Pragma("unroll") for (int n = 0; n < 2; ++n)                      \
                acc[(MHQ)*MH2 + i][(NHQ)*2 + n] =                              \
                    __builtin_amdgcn_mfma_f32_16x16x32_f16(                    \
                        af[i][ks], bf[n][ks], acc[(MHQ)*MH2 + i][(NHQ)*2 + n], \
                        0, 0, 0);                                              \
    __builtin_amdgcn_s_setprio(0);                                             \
    VMSTMT;                                                                    \
    __builtin_amdgcn_s_barrier();                                              \
  }

#define KTILE(J, KT)                                                           \
  {                                                                            \
    const int kn1_ = ((KT) + 1 < NK) ? (KT) + 1 : NK - 1;                      \
    const int kn2_ = ((KT) + 2 < NK) ? (KT) + 2 : NK - 1;                      \
    PHASE(J, 0, 0, true, true, STG_B(1 - (J), 0, kn1_), VM_NONE)               \
    PHASE(J, 0, 1, false, true, STG_A(1 - (J), 1, kn1_), VM_8)                 \
    PHASE(J, 1, 1, true, false, STG_A(J, 0, kn2_), VM_NONE)                    \
    PHASE(J, 1, 0, false, true, STG_B(J, 1, kn2_), VM_6)                       \
  }

  STG_A(0, 0, 0) STG_B(0, 0, 0) STG_B(0, 1, 0) STG_A(0, 1, 0)
  STG_A(1, 0, 1) STG_B(1, 1, 1)
  VM_6;
  __builtin_amdgcn_s_barrier();

#pragma unroll 1
  for (int kt = 0; kt < NK; kt += 2) {
    KTILE(0, kt)
    KTILE(1, kt + 1)
  }
  asm volatile("s_waitcnt vmcnt(0)" ::: "memory");
#undef KTILE
#undef PHASE
#undef VM_8
#undef VM_6
#undef VM_NONE
#undef STG_A
#undef STG_B

  float bcol[4];
#pragma unroll
  for (int n = 0; n < 4; ++n) bcol[n] = bias[n0 + (n * 4 + wc) * 16 + l15];
#pragma unroll
  for (int m = 0; m < MR; ++m) {
#pragma unroll
    for (int rr = 0; rr < 4; ++rr) {
      const size_t row = m0 + (m * 2 + wr) * 16 + grp * 4 + rr;
#pragma unroll
      for (int n = 0; n < 4; ++n) {
        const int col = n0 + (n * 4 + wc) * 16 + l15;
        float v = acc[m][n][rr] + bcol[n];
        const size_t idx = row * N + col;
        if (EPI == 0) {
          outh[idx] = (_Float16)v;
        } else if (EPI == 1) {
          float t2 = v + res[idx];
          outf[idx] = t2;
          outh[idx] = (_Float16)t2;
        } else if (EPI == 2) {
          float g = 0.5f * v * (1.0f + fast_erf(v * 0.70710678118654752f));
          outh[idx] = (_Float16)g;
        } else {
          outf[idx] = v + res[idx];
        }
      }
    }
  }
}

// ======== fat-phase tri-buffer GEMM: BM=256, BN=128, BK=64, 2 phases/K-tile ========
// EPI 0: outh=(f16)(acc+bias); 1: outh=(f16)(acc+bias+(float)res_f16);
// EPI 2: outh=(f16)gelu(acc+bias); 4: outf=acc+bias+(float)res_f16;
// EPI 5 (QKV): col<1024 -> Q scaled by 0.125*log2e; col<2048 -> qkv; else Vt (half4).
template <int EPI>
__global__ __launch_bounds__(512, 2) void k_gemmf(
    const _Float16* __restrict__ A, const _Float16* __restrict__ Bt,
    const float* __restrict__ bias, const void* __restrict__ res,
    float* __restrict__ outf, _Float16* __restrict__ outh, int M, int N, int K) {
  constexpr int AL = 256 * 64, BL = 128 * 64;
  constexpr int ABY = 32768, BBY = 16384, BBASE = 3 * ABY;
  __shared__ _Float16 lds[3 * (AL + BL)];
  const char* ldsc = (const char*)lds;

  const int tid = threadIdx.x;
  const int lane = tid & 63;
  const int w = tid >> 6, wr = w >> 1, wc = w & 1;
  const int l15 = lane & 15, grp = lane >> 4;

  const int gx = gridDim.x;
  const int nwg = gx * gridDim.y;
  const int lid = blockIdx.y * gx + blockIdx.x;
  const int wid = (lid & 7) * (nwg >> 3) + (lid >> 3);
  const int m0 = (wid / gx) * 256, n0 = (wid % gx) * 128;

  const int m2 = (l15 >> 2) & 1, m01 = l15 & 3;
  const int c0 = ((m2 << 2) | (grp ^ m01)) * 16;
  const int aoff0 = wr * 2048 + l15 * 128 + c0;
  const int aoff1 = aoff0 ^ 64;
  const int boff0 = wc * 2048 + l15 * 128 + c0;
  const int boff1 = boff0 ^ 64;

  const int srow = tid >> 3;
  const int scs8 = ((tid & 7) ^ (srow & 7)) * 8;
  const int NK = K >> 6;

  const _Float16* aG = A + (size_t)(m0 + srow) * K + scs8;
  const _Float16* bG = Bt + (size_t)(n0 + srow) * K + scs8;

  f32x4 acc[4][4] = {};

#define FSTG_A(JJ, HH, KN)                                                     \
  _Pragma("unroll") for (int s = 0; s < 2; ++s)                                \
      glds16(aG + (size_t)((HH)*128 + s * 64) * K + (size_t)(KN)*64,           \
             lds + (JJ)*AL + ((HH)*128 + s * 64) * 64 + tid * 8);
#define FSTG_B(JJ, HH, KN)                                                     \
  glds16(bG + (size_t)((HH)*64) * K + (size_t)(KN)*64,                         \
         lds + 3 * AL + (JJ)*BL + (HH)*64 * 64 + tid * 8);

#define FPHASE(PA, PB, AO, BO, STGSTMT, VMSTMT)                                \
  {                                                                            \
    half8 af_[4], bf_[4];                                                      \
    _Pragma("unroll") for (int m = 0; m < 4; ++m)                              \
        af_[m] = *(const half8*)((PA) + m * 8192 + (AO));                      \
    _Pragma("unroll") for (int n = 0; n < 4; ++n)                              \
        bf_[n] = *(const half8*)((PB) + n * 4096 + (BO));                      \
    STGSTMT;                                                                   \
    __builtin_amdgcn_s_barrier();                                              \
    asm volatile("s_waitcnt lgkmcnt(0)");                                      \
    __builtin_amdgcn_sched_barrier(0);                                         \
    __builtin_amdgcn_s_setprio(1);                                             \
    _Pragma("unroll") for (int m = 0; m < 4; ++m)                              \
        _Pragma("unroll") for (int n = 0; n < 4; ++n)                          \
            acc[m][n] = __builtin_amdgcn_mfma_f32_16x16x32_f16(                \
                af_[m], bf_[n], acc[m][n], 0, 0, 0);                           \
    __builtin_amdgcn_s_setprio(0);                                             \
    VMSTMT;                                                                    \
    __builtin_amdgcn_s_barrier();                                              \
  }

  FSTG_A(0, 0, 0) FSTG_A(0, 1, 0) FSTG_B(0, 0, 0) FSTG_B(0, 1, 0)
  FSTG_A(1, 0, 1) FSTG_A(1, 1, 1) FSTG_B(1, 0, 1) FSTG_B(1, 1, 1)
  asm volatile("s_waitcnt vmcnt(6)" ::: "memory");
  __builtin_amdgcn_s_barrier();

  int j = 0, j2 = 2;
#pragma unroll 1
  for (int kt = 0; kt < NK; ++kt) {
    const int kn = (kt + 2 < NK) ? kt + 2 : NK - 1;
    const char* pa = ldsc + j * ABY;
    const char* pb = ldsc + BBASE + j * BBY;
    FPHASE(pa, pb, aoff0, boff0, { FSTG_A(j2, 0, kn) FSTG_B(j2, 0, kn) }, )
    FPHASE(pa, pb, aoff1, boff1, { FSTG_A(j2, 1, kn) FSTG_B(j2, 1, kn) },
           asm volatile("s_waitcnt vmcnt(6)" ::: "memory");)
    j = (j == 2) ? 0 : j + 1;
    j2 = (j2 == 2) ? 0 : j2 + 1;
  }
  asm volatile("s_waitcnt vmcnt(0)" ::: "memory");
#undef FPHASE
#undef FSTG_A
#undef FSTG_B

  float bcol[4];
#pragma unroll
  for (int n = 0; n < 4; ++n) bcol[n] = bias[n0 + (n * 2 + wc) * 16 + l15];
  if (EPI == 5) {
    const float QSC = 0.125f * 1.44269504088896f;
    _Float16* vt = (_Float16*)outf;
#pragma unroll
    for (int m = 0; m < 4; ++m) {
#pragma unroll
      for (int n = 0; n < 4; ++n) {
        const int col = n0 + (n * 2 + wc) * 16 + l15;
        const size_t row0 = m0 + (m * 4 + wr) * 16 + grp * 4;
        if (col < 2048) {
          const float scl = (col < 1024) ? QSC : 1.0f;
#pragma unroll
          for (int rr = 0; rr < 4; ++rr)
            outh[(row0 + rr) * (size_t)N + col] = (_Float16)((acc[m][n][rr] + bcol[n]) * scl);
        } else {
          const int b = (int)(row0 >> 10), s = (int)(row0 & 1023);
          const int cv = col - 2048, hh = cv >> 6, e = cv & 63;
          half4 pk;
#pragma unroll
          for (int rr = 0; rr < 4; ++rr) pk[rr] = (_Float16)(acc[m][n][rr] + bcol[n]);
          *(half4*)&vt[((size_t)((b << 4) | hh) * 64 + e) * 1024 + s] = pk;
        }
      }
    }
    return;
  }
#pragma unroll
  for (int m = 0; m < 4; ++m) {
#pragma unroll
    for (int rr = 0; rr < 4; ++rr) {
      const size_t row = m0 + (m * 4 + wr) * 16 + grp * 4 + rr;
#pragma unroll
      for (int n = 0; n < 4; ++n) {
        const int col = n0 + (n * 2 + wc) * 16 + l15;
        float v = acc[m][n][rr] + bcol[n];
        const size_t idx = row * N + col;
        if (EPI == 0) {
          outh[idx] = (_Float16)v;
        } else if (EPI == 1) {
          float t2 = v + (float)((const _Float16*)res)[idx];
          outh[idx] = (_Float16)t2;
        } else if (EPI == 2) {
          float g = 0.5f * v * (1.0f + fast_erf(v * 0.70710678118654752f));
          outh[idx] = (_Float16)g;
        } else {
          float t2 = v + (float)((const _Float16*)res)[idx];
          outf[idx] = t2;
        }
      }
    }
  }
}

// ---- flash attention: dbuf KVBLK=64, counted vmcnt, 2 Q-tiles/block ----
__global__ __launch_bounds__(256) void k_attn(const _Float16* __restrict__ qkv,
                                              const _Float16* __restrict__ Vt,
                                              _Float16* __restrict__ ctx) {
  __shared__ _Float16 Ks[2][64 * 64];
  __shared__ _Float16 Vs[2][64 * 64];
  __shared__ _Float16 Ps[4][16 * 68];
  const int tid = threadIdx.x;
  const int lane = tid & 63, w = tid >> 6;
  const int l15 = lane & 15, grp = lane >> 4;
  const int d = blockIdx.x;
  const int bh = (d & 7) * 16 + ((d >> 3) & 15);
  const int q0 = (d >> 7) << 7;
  const int b = bh >> 4, h = bh & 15;

  half8 qf[2][2];
#pragma unroll
  for (int qs = 0; qs < 2; ++qs) {
    const _Float16* qp =
        qkv + (size_t)(b * 1024 + q0 + qs * 64 + w * 16 + l15) * 3072 + h * 64 + grp * 8;
    qf[qs][0] = *(const half8*)qp;
    qf[qs][1] = *(const half8*)(qp + 32);
  }
  half8 ones;
#pragma unroll
  for (int i = 0; i < 8; ++i) ones[i] = (_Float16)1.0f;

  f32x4 octx[2][4] = {};
  f32x4 lsum[2] = {};
  float mrun[2] = {-1e30f, -1e30f};

#define ASTAGE(BB, S0)                                                         \
  _Pragma("unroll") for (int i = 0; i < 2; ++i) {                              \
    int sr = i * 32 + (tid >> 3);                                              \
    int c8 = (tid & 7) ^ (sr & 7);                                             \
    glds16(qkv + (size_t)(b * 1024 + (S0) + sr) * 3072 + 1024 + h * 64 + c8 * 8, \
           &Ks[BB][0] + i * 2048 + tid * 8);                                   \
    glds16(Vt + (size_t)(bh * 64 + sr) * 1024 + (S0) + c8 * 8,                 \
           &Vs[BB][0] + i * 2048 + tid * 8);                                   \
  }

  ASTAGE(0, 0)
#pragma unroll 1
  for (int kt = 0; kt < 16; ++kt) {
    const int bb = kt & 1;
    if (kt + 1 < 16) {
      ASTAGE(1 - bb, (kt + 1) * 64)
      asm volatile("s_waitcnt vmcnt(4)" ::: "memory");
    } else {
      asm volatile("s_waitcnt vmcnt(0)" ::: "memory");
    }
    __builtin_amdgcn_s_barrier();
#pragma unroll
    for (int qs = 0; qs < 2; ++qs) {
      f32x4 sacc[4] = {};
      __builtin_amdgcn_s_setprio(1);
#pragma unroll
      for (int ks = 0; ks < 2; ++ks)
#pragma unroll
        for (int f = 0; f < 4; ++f) {
          int sr = f * 16 + l15;
          half8 kf = *(const half8*)&Ks[bb][sr * 64 + ((ks * 32 + grp * 8) ^ ((sr & 7) * 8))];
          sacc[f] = __builtin_amdgcn_mfma_f32_16x16x32_f16(kf, qf[qs][ks], sacc[f], 0, 0, 0);
        }
      __builtin_amdgcn_s_setprio(0);
      float tmax = -1e30f;
#pragma unroll
      for (int f = 0; f < 4; ++f)
#pragma unroll
        for (int r = 0; r < 4; ++r) tmax = fmaxf(tmax, sacc[f][r]);
      tmax = fmaxf(tmax, __shfl_xor(tmax, 16));
      tmax = fmaxf(tmax, __shfl_xor(tmax, 32));
      if (!__all(tmax <= mrun[qs] + 8.0f)) {
        float mnew = fmaxf(mrun[qs], tmax);
        float corr = exp2f(mrun[qs] - mnew);
        mrun[qs] = mnew;
#pragma unroll
        for (int r = 0; r < 4; ++r) {
          float cq = __shfl(corr, (lane & 48) + grp * 4 + r);
#pragma unroll
          for (int jf = 0; jf < 4; ++jf) octx[qs][jf][r] *= cq;
          lsum[qs][r] *= cq;
        }
      }
#pragma unroll
      for (int f = 0; f < 4; ++f) {
        half4 pk;
#pragma unroll
        for (int r = 0; r < 4; ++r) pk[r] = (_Float16)exp2f(sacc[f][r] - mrun[qs]);
        *(half4*)&Ps[w][l15 * 68 + f * 16 + grp * 4] = pk;
      }
      __builtin_amdgcn_s_setprio(1);
#pragma unroll
      for (int ks2 = 0; ks2 < 2; ++ks2) {
        half8 pa = *(const half8*)&Ps[w][l15 * 68 + ks2 * 32 + grp * 8];
        lsum[qs] = __builtin_amdgcn_mfma_f32_16x16x32_f16(pa, ones, lsum[qs], 0, 0, 0);
#pragma unroll
        for (int jf = 0; jf < 4; ++jf) {
          int er = jf * 16 + l15;
          half8 vb = *(const half8*)&Vs[bb][er * 64 + ((ks2 * 32 + grp * 8) ^ ((er & 7) * 8))];
          octx[qs][jf] = __builtin_amdgcn_mfma_f32_16x16x32_f16(pa, vb, octx[qs][jf], 0, 0, 0);
        }
      }
      __builtin_amdgcn_s_setprio(0);
    }
    __builtin_amdgcn_s_barrier();
  }
#undef ASTAGE
#pragma unroll
  for (int qs = 0; qs < 2; ++qs) {
#pragma unroll
    for (int r = 0; r < 4; ++r) {
      float inv = 1.0f / lsum[qs][r];
      const size_t row = b * 1024 + q0 + qs * 64 + w * 16 + grp * 4 + r;
#pragma unroll
      for (int jf = 0; jf < 4; ++jf)
        ctx[row * 1024 + h * 64 + jf * 16 + l15] = (_Float16)(octx[qs][jf][r] * inv);
    }
  }
}

// ---------------- LayerNorm ----------------
__global__ __launch_bounds__(256) void k_ln(const float* xin, const float* __restrict__ gamma,
                                            const float* __restrict__ beta, float* out) {
  __shared__ float red[8];
  const int tid = threadIdx.x;
  const size_t row = blockIdx.x;
  f32x4 v = *(const f32x4*)&xin[row * 1024 + tid * 4];
  float s = v[0] + v[1] + v[2] + v[3];
  float s2 = v[0] * v[0] + v[1] * v[1] + v[2] * v[2] + v[3] * v[3];
#pragma unroll
  for (int o = 32; o >= 1; o >>= 1) {
    s += __shfl_xor(s, o);
    s2 += __shfl_xor(s2, o);
  }
  if ((tid & 63) == 0) { red[tid >> 6] = s; red[4 + (tid >> 6)] = s2; }
  __syncthreads();
  s = red[0] + red[1] + red[2] + red[3];
  s2 = red[4] + red[5] + red[6] + red[7];
  float mu = s * (1.0f / 1024.0f);
  float var = s2 * (1.0f / 1024.0f) - mu * mu;
  float rs = rsqrtf(var + 1e-5f);
  f32x4 g = *(const f32x4*)&gamma[tid * 4];
  f32x4 bt = *(const f32x4*)&beta[tid * 4];
  f32x4 o4;
#pragma unroll
  for (int r = 0; r < 4; ++r) o4[r] = (v[r] - mu) * rs * g[r] + bt[r];
  *(f32x4*)&out[row * 1024 + tid * 4] = o4;
}

extern "C" void kernel_launch(void* const* d_in, const int* in_sizes, int n_in,
                              void* d_out, int out_size, void* d_ws, size_t ws_size,
                              hipStream_t stream) {
  (void)in_sizes; (void)n_in; (void)out_size; (void)ws_size;
  const float* x  = (const float*)d_in[0];
  const float* Wq = (const float*)d_in[1];  const float* bq = (const float*)d_in[2];
  const float* Wk = (const float*)d_in[3];  const float* bk = (const float*)d_in[4];
  const float* Wv = (const float*)d_in[5];  const float* bv = (const float*)d_in[6];
  const float* Wo = (const float*)d_in[7];  const float* bo = (const float*)d_in[8];
  const float* W1 = (const float*)d_in[9];  const float* b1 = (const float*)d_in[10];
  const float* W2 = (const float*)d_in[11]; const float* b2 = (const float*)d_in[12];
  const float* gamma = (const float*)d_in[13];
  const float* beta  = (const float*)d_in[14];
  float* out = (float*)d_out;

  char* p = (char*)d_ws;
  _Float16* xb    = (_Float16*)p;  p += (size_t)16 << 20;   // x f16 (NOT reused)
  _Float16* qkv   = (_Float16*)p;
  _Float16* hbuf  = (_Float16*)p;  p += (size_t)48 << 20;   // qkv; reused as h after attn
  _Float16* Vt    = (_Float16*)p;  p += (size_t)16 << 20;
  _Float16* ctx   = (_Float16*)p;  p += (size_t)16 << 20;   // dedicated ctx buffer
  _Float16* Wqkvt = (_Float16*)p;  p += (size_t)3072 * 1024 * 2;
  _Float16* Wot   = (_Float16*)p;  p += (size_t)1024 * 1024 * 2;
  _Float16* W1t   = (_Float16*)p;  p += (size_t)4096 * 1024 * 2;
  _Float16* W2t   = (_Float16*)p;  p += (size_t)4096 * 1024 * 2;
  float*    bqkv  = (float*)p;     p += (size_t)3072 * 4;
  _Float16* x1b   = (_Float16*)p;  p += (size_t)16 << 20;

  // fused prep: cvt (4096) + transposes (3072) + biascat (12) = 7180 blocks
  k_prep<<<7180, 256, 0, stream>>>(x, xb, Wq, Wk, Wv, Wo, W1, W2,
                                   Wqkvt, Wot, W1t, W2t, bq, bk, bv, bqkv);

  // QKV: fat128 + fused V-transpose + Q-prescale -> 24x32 = 768 blocks
  k_gemmf<5><<<dim3(24, 32), 512, 0, stream>>>(xb, Wqkvt, bqkv, nullptr, (float*)Vt, qkv,
                                               8192, 3072, 1024);
  // attention: XCD-local 1-D grid, dbuf KV, 2 Q-tiles/block -> 1024 blocks
  k_attn<<<1024, 256, 0, stream>>>(qkv, Vt, ctx);
  // x1b = (f16)(xb + ctx@Wo + bo) : fat128 -> 8x32 = 256 blocks (res = intact xb)
  k_gemmf<1><<<dim3(8, 32), 512, 0, stream>>>(ctx, Wot, bo, xb, nullptr, x1b,
                                              8192, 1024, 1024);
  // h = gelu(x1b@W1 + b1) : quadrant + deep spread staging -> 16x32 = 512 blocks
  k_gemm8<256, 2><<<dim3(16, 32), 512, 0, stream>>>(x1b, W1t, b1, nullptr, nullptr, hbuf,
                                                    8192, 4096, 1024);
  // out = x1b + h@W2 + b2 (f32) : fat128, K=4096 -> 8x32 = 256 blocks
  k_gemmf<4><<<dim3(8, 32), 512, 0, stream>>>(hbuf, W2t, b2, x1b, out, nullptr,
                                              8192, 1024, 4096);
  k_ln<<<8192, 256, 0, stream>>>(out, gamma, beta, out);
}

// Round 17
// 331.861 us; speedup vs baseline: 1.0352x; 1.0352x over previous
//
#include <hip/hip_runtime.h>
#include <cmath>

typedef __attribute__((ext_vector_type(8))) _Float16 half8;
typedef __attribute__((ext_vector_type(4))) _Float16 half4;
typedef __attribute__((ext_vector_type(4))) float f32x4;

__device__ __forceinline__ void glds16(const void* g, void* l) {
  __builtin_amdgcn_global_load_lds(
      (__attribute__((address_space(1))) const void*)g,
      (__attribute__((address_space(3))) void*)l, 16, 0, 0);
}

// A&S 7.1.26, |err| <= 1.5e-7
__device__ __forceinline__ float fast_erf(float x) {
  float ax = fabsf(x);
  float t = 1.0f / (1.0f + 0.3275911f * ax);
  float y = t * (0.254829592f +
            t * (-0.284496736f +
            t * (1.421413741f +
            t * (-1.453152027f + t * 1.061405429f))));
  float r = 1.0f - y * __expf(-ax * ax);
  return copysignf(r, x);
}

// ======== fused prep: x cvt (4096 blk) + 6 weight transposes (3072 blk) + biascat (12 blk) ========
__global__ __launch_bounds__(256) void k_prep(
    const float* __restrict__ x, _Float16* __restrict__ xb,
    const float* __restrict__ Wq, const float* __restrict__ Wk,
    const float* __restrict__ Wv, const float* __restrict__ Wo,
    const float* __restrict__ W1, const float* __restrict__ W2,
    _Float16* __restrict__ Wqkvt, _Float16* __restrict__ Wot,
    _Float16* __restrict__ W1t, _Float16* __restrict__ W2t,
    const float* __restrict__ bq, const float* __restrict__ bk,
    const float* __restrict__ bv, float* __restrict__ bqkv) {
  __shared__ float t[64][65];
  const int tid = threadIdx.x;
  const int bid = blockIdx.x;
  if (bid < 4096) {  // x f32 -> f16
    int i = (bid * 256 + tid) * 8;
    const f32x4* p = (const f32x4*)(x + i);
    f32x4 a = p[0], b = p[1];
    half8 h;
    h[0] = (_Float16)a[0]; h[1] = (_Float16)a[1]; h[2] = (_Float16)a[2]; h[3] = (_Float16)a[3];
    h[4] = (_Float16)b[0]; h[5] = (_Float16)b[1]; h[6] = (_Float16)b[2]; h[7] = (_Float16)b[3];
    *(half8*)(xb + i) = h;
    return;
  }
  const int tt = bid - 4096;
  if (tt >= 3072) {  // biascat (12 blocks)
    int i = (tt - 3072) * 256 + tid;
    const float* s = i < 1024 ? bq : (i < 2048 ? bk : bv);
    bqkv[i] = s[i & 1023];
    return;
  }
  // weight transpose: W [K,N] f32 -> Wt [N,K] f16, 64x64 tile
  const float* W; _Float16* Wt; int K, N, bx, by;
  if (tt < 1024) {
    const int wsel = tt >> 8, r = tt & 255;
    W = wsel == 0 ? Wq : wsel == 1 ? Wk : wsel == 2 ? Wv : Wo;
    Wt = wsel < 3 ? Wqkvt + (size_t)wsel * 1024 * 1024 : Wot;
    K = 1024; N = 1024; bx = r & 15; by = r >> 4;
  } else if (tt < 2048) {
    const int r = tt - 1024;
    W = W1; Wt = W1t; K = 1024; N = 4096; bx = r & 63; by = r >> 6;
  } else {
    const int r = tt - 2048;
    W = W2; Wt = W2t; K = 4096; N = 1024; bx = r & 15; by = r >> 4;
  }
  const int k0 = by << 6, n0 = bx << 6;
  {
    const int r = tid >> 2, q = tid & 3;
    const float* src = &W[(size_t)(k0 + r) * N + n0 + q * 16];
    f32x4 v0 = *(const f32x4*)(src);
    f32x4 v1 = *(const f32x4*)(src + 4);
    f32x4 v2 = *(const f32x4*)(src + 8);
    f32x4 v3 = *(const f32x4*)(src + 12);
    float* d = &t[r][q * 16];
#pragma unroll
    for (int j = 0; j < 4; ++j) d[j] = v0[j];
#pragma unroll
    for (int j = 0; j < 4; ++j) d[4 + j] = v1[j];
#pragma unroll
    for (int j = 0; j < 4; ++j) d[8 + j] = v2[j];
#pragma unroll
    for (int j = 0; j < 4; ++j) d[12 + j] = v3[j];
  }
  __syncthreads();
#pragma unroll
  for (int p = 0; p < 2; ++p) {
    const int c = p * 256 + tid;
    const int row = c >> 3, c8 = c & 7;
    half8 hv;
#pragma unroll
    for (int j = 0; j < 8; ++j) hv[j] = (_Float16)t[c8 * 8 + j][row];
    *(half8*)&Wt[(size_t)(n0 + row) * K + k0 + c8 * 8] = hv;
  }
}

// ======== quadrant 8-phase GEMM: BM=256,BN=256, BK=64, dbuf, DEEP spread staging ========
template <int BM, int EPI>
__global__ __launch_bounds__(512, 2) void k_gemm8(
    const _Float16* __restrict__ A, const _Float16* __restrict__ Bt,
    const float* __restrict__ bias, const float* __restrict__ res,
    float* __restrict__ outf, _Float16* __restrict__ outh, int M, int N, int K) {
  constexpr int MR = BM / 32;
  constexpr int MH2 = MR / 2;
  constexpr int AL = BM * 64;
  constexpr int BL = 256 * 64;
  constexpr int ABYTES = BM * 128;
  constexpr int BBYTES = 256 * 128;
  constexpr int AB2 = 2 * ABYTES;
  __shared__ _Float16 lds[2 * (AL + BL)];
  const char* ldsc = (const char*)lds;

  const int tid = threadIdx.x;
  const int lane = tid & 63;
  const int w = tid >> 6, wr = w >> 2, wc = w & 3;
  const int l15 = lane & 15, grp = lane >> 4;

  const int gx = gridDim.x;
  const int nwg = gx * gridDim.y;
  const int lid = blockIdx.y * gx + blockIdx.x;
  const int wid = (lid & 7) * (nwg >> 3) + (lid >> 3);
  const int m0 = (wid / gx) * BM, n0 = (wid % gx) * 256;

  const int m2 = (l15 >> 2) & 1, m01 = l15 & 3;
  const int chunk0 = (m2 << 2) | (grp ^ m01);
  const int aoff0 = wr * 2048 + l15 * 128 + chunk0 * 16;
  const int aoff1 = aoff0 ^ 64;
  const int boff0 = wc * 2048 + l15 * 128 + chunk0 * 16;
  const int boff1 = boff0 ^ 64;

  const int srow = tid >> 3;
  const int scs8 = ((tid & 7) ^ (srow & 7)) * 8;
  const int NK = K >> 6;

  f32x4 acc[MR][4] = {};
  half8 af[MH2][2], bf[2][2];

#define STG_A(J, MHH, KN)                                                      \
  _Pragma("unroll") for (int s = 0; s < BM / 128; ++s)                         \
      glds16(A + (size_t)(m0 + (MHH) * (BM / 2) + s * 64 + srow) * K +         \
                 (size_t)(KN)*64 + scs8,                                       \
             lds + (J)*AL + ((MHH) * (BM / 2) + s * 64) * 64 + tid * 8);
#define STG_B(J, NHH, KN)                                                      \
  _Pragma("unroll") for (int s = 0; s < 2; ++s)                                \
      glds16(Bt + (size_t)(n0 + (NHH)*128 + s * 64 + srow) * K +               \
                  (size_t)(KN)*64 + scs8,                                      \
             lds + 2 * AL + (J)*BL + ((NHH)*128 + s * 64) * 64 + tid * 8);

#define VM_8 asm volatile("s_waitcnt vmcnt(8)" ::: "memory")
#define VM_6 asm volatile("s_waitcnt vmcnt(6)" ::: "memory")
#define VM_NONE

#define PHASE(J, MHQ, NHQ, RA, RB, STGSTMT, VMSTMT)                            \
  {                                                                            \
    if constexpr (RA) {                                                        \
      _Pragma("unroll") for (int i = 0; i < MH2; ++i) {                        \
        af[i][0] = *(const half8*)(ldsc + (J)*ABYTES +                         \
                                   ((MHQ)*MH2 + i) * 4096 + aoff0);            \
        af[i][1] = *(const half8*)(ldsc + (J)*ABYTES +                         \
                                   ((MHQ)*MH2 + i) * 4096 + aoff1);            \
      }                                                                        \
    }                                                                          \
    if constexpr (RB) {                                                        \
      _Pragma("unroll") for (int n = 0; n < 2; ++n) {                          \
        bf[n][0] = *(const half8*)(ldsc + AB2 + (J)*BBYTES +                   \
                                   ((NHQ)*2 + n) * 8192 + boff0);              \
        bf[n][1] = *(const half8*)(ldsc + AB2 + (J)*BBYTES +                   \
                                   ((NHQ)*2 + n) * 8192 + boff1);              \
      }                                                                        \
    }                                                                          \
    STGSTMT;                                                                   \
    __builtin_amdgcn_s_barrier();                                              \
    asm volatile("s_waitcnt lgkmcnt(0)");                                      \
    __builtin_amdgcn_sched_barrier(0);                                         \
    __builtin_amdgcn_s_setprio(1);                                             \
    _Pragma("unroll") for (int ks = 0; ks < 2; ++ks)                           \
        _Pragma("unroll") for (int i = 0; i < MH2; ++i)                        \
            _Pragma("unroll") for (int n = 0; n < 2; ++n)                      \
                acc[(MHQ)*MH2 + i][(NHQ)*2 + n] =                              \
                    __builtin_amdgcn_mfma_f32_16x16x32_f16(                    \
                        af[i][ks], bf[n][ks], acc[(MHQ)*MH2 + i][(NHQ)*2 + n], \
                        0, 0, 0);                                              \
    __builtin_amdgcn_s_setprio(0);                                             \
    VMSTMT;                                                                    \
    __builtin_amdgcn_s_barrier();                                              \
  }

#define KTILE(J, KT)                                                           \
  {                                                                            \
    const int kn1_ = ((KT) + 1 < NK) ? (KT) + 1 : NK - 1;                      \
    const int kn2_ = ((KT) + 2 < NK) ? (KT) + 2 : NK - 1;                      \
    PHASE(J, 0, 0, true, true, STG_B(1 - (J), 0, kn1_), VM_NONE)               \
    PHASE(J, 0, 1, false, true, STG_A(1 - (J), 1, kn1_), VM_8)                 \
    PHASE(J, 1, 1, true, false, STG_A(J, 0, kn2_), VM_NONE)                    \
    PHASE(J, 1, 0, false, true, STG_B(J, 1, kn2_), VM_6)                       \
  }

  STG_A(0, 0, 0) STG_B(0, 0, 0) STG_B(0, 1, 0) STG_A(0, 1, 0)
  STG_A(1, 0, 1) STG_B(1, 1, 1)
  VM_6;
  __builtin_amdgcn_s_barrier();

#pragma unroll 1
  for (int kt = 0; kt < NK; kt += 2) {
    KTILE(0, kt)
    KTILE(1, kt + 1)
  }
  asm volatile("s_waitcnt vmcnt(0)" ::: "memory");
#undef KTILE
#undef PHASE
#undef VM_8
#undef VM_6
#undef VM_NONE
#undef STG_A
#undef STG_B

  float bcol[4];
#pragma unroll
  for (int n = 0; n < 4; ++n) bcol[n] = bias[n0 + (n * 4 + wc) * 16 + l15];
#pragma unroll
  for (int m = 0; m < MR; ++m) {
#pragma unroll
    for (int rr = 0; rr < 4; ++rr) {
      const size_t row = m0 + (m * 2 + wr) * 16 + grp * 4 + rr;
#pragma unroll
      for (int n = 0; n < 4; ++n) {
        const int col = n0 + (n * 4 + wc) * 16 + l15;
        float v = acc[m][n][rr] + bcol[n];
        const size_t idx = row * N + col;
        if (EPI == 0) {
          outh[idx] = (_Float16)v;
        } else if (EPI == 1) {
          float t2 = v + res[idx];
          outf[idx] = t2;
          outh[idx] = (_Float16)t2;
        } else if (EPI == 2) {
          float g = 0.5f * v * (1.0f + fast_erf(v * 0.70710678118654752f));
          outh[idx] = (_Float16)g;
        } else {
          outf[idx] = v + res[idx];
        }
      }
    }
  }
}

// ======== fat-phase tri-buffer GEMM: BM=256, BN=128, BK=64, 2 phases/K-tile ========
// EPI 0: outh=(f16)(acc+bias); 1: outh=(f16)(acc+bias+(float)res_f16);
// EPI 2: outh=(f16)gelu(acc+bias); 4: outf=acc+bias+(float)res_f16;
// EPI 5 (QKV): col<1024 -> Q scaled by 0.125*log2e; col<2048 -> qkv; else Vt (half4).
template <int EPI>
__global__ __launch_bounds__(512, 2) void k_gemmf(
    const _Float16* __restrict__ A, const _Float16* __restrict__ Bt,
    const float* __restrict__ bias, const void* __restrict__ res,
    float* __restrict__ outf, _Float16* __restrict__ outh, int M, int N, int K) {
  constexpr int AL = 256 * 64, BL = 128 * 64;
  constexpr int ABY = 32768, BBY = 16384, BBASE = 3 * ABY;
  __shared__ _Float16 lds[3 * (AL + BL)];
  const char* ldsc = (const char*)lds;

  const int tid = threadIdx.x;
  const int lane = tid & 63;
  const int w = tid >> 6, wr = w >> 1, wc = w & 1;
  const int l15 = lane & 15, grp = lane >> 4;

  const int gx = gridDim.x;
  const int nwg = gx * gridDim.y;
  const int lid = blockIdx.y * gx + blockIdx.x;
  const int wid = (lid & 7) * (nwg >> 3) + (lid >> 3);
  const int m0 = (wid / gx) * 256, n0 = (wid % gx) * 128;

  const int m2 = (l15 >> 2) & 1, m01 = l15 & 3;
  const int c0 = ((m2 << 2) | (grp ^ m01)) * 16;
  const int aoff0 = wr * 2048 + l15 * 128 + c0;
  const int aoff1 = aoff0 ^ 64;
  const int boff0 = wc * 2048 + l15 * 128 + c0;
  const int boff1 = boff0 ^ 64;

  const int srow = tid >> 3;
  const int scs8 = ((tid & 7) ^ (srow & 7)) * 8;
  const int NK = K >> 6;

  const _Float16* aG = A + (size_t)(m0 + srow) * K + scs8;
  const _Float16* bG = Bt + (size_t)(n0 + srow) * K + scs8;

  f32x4 acc[4][4] = {};

#define FSTG_A(JJ, HH, KN)                                                     \
  _Pragma("unroll") for (int s = 0; s < 2; ++s)                                \
      glds16(aG + (size_t)((HH)*128 + s * 64) * K + (size_t)(KN)*64,           \
             lds + (JJ)*AL + ((HH)*128 + s * 64) * 64 + tid * 8);
#define FSTG_B(JJ, HH, KN)                                                     \
  glds16(bG + (size_t)((HH)*64) * K + (size_t)(KN)*64,                         \
         lds + 3 * AL + (JJ)*BL + (HH)*64 * 64 + tid * 8);

#define FPHASE(PA, PB, AO, BO, STGSTMT, VMSTMT)                                \
  {                                                                            \
    half8 af_[4], bf_[4];                                                      \
    _Pragma("unroll") for (int m = 0; m < 4; ++m)                              \
        af_[m] = *(const half8*)((PA) + m * 8192 + (AO));                      \
    _Pragma("unroll") for (int n = 0; n < 4; ++n)                              \
        bf_[n] = *(const half8*)((PB) + n * 4096 + (BO));                      \
    STGSTMT;                                                                   \
    __builtin_amdgcn_s_barrier();                                              \
    asm volatile("s_waitcnt lgkmcnt(0)");                                      \
    __builtin_amdgcn_sched_barrier(0);                                         \
    __builtin_amdgcn_s_setprio(1);                                             \
    _Pragma("unroll") for (int m = 0; m < 4; ++m)                              \
        _Pragma("unroll") for (int n = 0; n < 4; ++n)                          \
            acc[m][n] = __builtin_amdgcn_mfma_f32_16x16x32_f16(                \
                af_[m], bf_[n], acc[m][n], 0, 0, 0);                           \
    __builtin_amdgcn_s_setprio(0);                                             \
    VMSTMT;                                                                    \
    __builtin_amdgcn_s_barrier();                                              \
  }

  FSTG_A(0, 0, 0) FSTG_A(0, 1, 0) FSTG_B(0, 0, 0) FSTG_B(0, 1, 0)
  FSTG_A(1, 0, 1) FSTG_A(1, 1, 1) FSTG_B(1, 0, 1) FSTG_B(1, 1, 1)
  asm volatile("s_waitcnt vmcnt(6)" ::: "memory");
  __builtin_amdgcn_s_barrier();

  int j = 0, j2 = 2;
#pragma unroll 1
  for (int kt = 0; kt < NK; ++kt) {
    const int kn = (kt + 2 < NK) ? kt + 2 : NK - 1;
    const char* pa = ldsc + j * ABY;
    const char* pb = ldsc + BBASE + j * BBY;
    FPHASE(pa, pb, aoff0, boff0, { FSTG_A(j2, 0, kn) FSTG_B(j2, 0, kn) }, )
    FPHASE(pa, pb, aoff1, boff1, { FSTG_A(j2, 1, kn) FSTG_B(j2, 1, kn) },
           asm volatile("s_waitcnt vmcnt(6)" ::: "memory");)
    j = (j == 2) ? 0 : j + 1;
    j2 = (j2 == 2) ? 0 : j2 + 1;
  }
  asm volatile("s_waitcnt vmcnt(0)" ::: "memory");
#undef FPHASE
#undef FSTG_A
#undef FSTG_B

  float bcol[4];
#pragma unroll
  for (int n = 0; n < 4; ++n) bcol[n] = bias[n0 + (n * 2 + wc) * 16 + l15];
  if (EPI == 5) {
    const float QSC = 0.125f * 1.44269504088896f;
    _Float16* vt = (_Float16*)outf;
#pragma unroll
    for (int m = 0; m < 4; ++m) {
#pragma unroll
      for (int n = 0; n < 4; ++n) {
        const int col = n0 + (n * 2 + wc) * 16 + l15;
        const size_t row0 = m0 + (m * 4 + wr) * 16 + grp * 4;
        if (col < 2048) {
          const float scl = (col < 1024) ? QSC : 1.0f;
#pragma unroll
          for (int rr = 0; rr < 4; ++rr)
            outh[(row0 + rr) * (size_t)N + col] = (_Float16)((acc[m][n][rr] + bcol[n]) * scl);
        } else {
          const int b = (int)(row0 >> 10), s = (int)(row0 & 1023);
          const int cv = col - 2048, hh = cv >> 6, e = cv & 63;
          half4 pk;
#pragma unroll
          for (int rr = 0; rr < 4; ++rr) pk[rr] = (_Float16)(acc[m][n][rr] + bcol[n]);
          *(half4*)&vt[((size_t)((b << 4) | hh) * 64 + e) * 1024 + s] = pk;
        }
      }
    }
    return;
  }
#pragma unroll
  for (int m = 0; m < 4; ++m) {
#pragma unroll
    for (int rr = 0; rr < 4; ++rr) {
      const size_t row = m0 + (m * 4 + wr) * 16 + grp * 4 + rr;
#pragma unroll
      for (int n = 0; n < 4; ++n) {
        const int col = n0 + (n * 2 + wc) * 16 + l15;
        float v = acc[m][n][rr] + bcol[n];
        const size_t idx = row * N + col;
        if (EPI == 0) {
          outh[idx] = (_Float16)v;
        } else if (EPI == 1) {
          float t2 = v + (float)((const _Float16*)res)[idx];
          outh[idx] = (_Float16)t2;
        } else if (EPI == 2) {
          float g = 0.5f * v * (1.0f + fast_erf(v * 0.70710678118654752f));
          outh[idx] = (_Float16)g;
        } else {
          float t2 = v + (float)((const _Float16*)res)[idx];
          outf[idx] = t2;
        }
      }
    }
  }
}

// ---- flash attention (r14-measured version): 4 waves, 2 Q-tiles/block, KV-tile 128 ----
// Q pre-scaled by 0.125*log2e. Row-sum via ones-column MFMA. Defer-max THR=8.
// Grid 1024 1-D: bh=(d&7)*16+((d>>3)&15), qt=d>>7 -> each XCD owns 16 bh.
__global__ __launch_bounds__(256) void k_attn(const _Float16* __restrict__ qkv,
                                              const _Float16* __restrict__ Vt,
                                              _Float16* __restrict__ ctx) {
  __shared__ _Float16 Ks[128 * 64];
  __shared__ _Float16 Vs[64 * 128];
  __shared__ _Float16 Ps[4][16 * 136];
  const int tid = threadIdx.x;
  const int lane = tid & 63, w = tid >> 6;
  const int l15 = lane & 15, grp = lane >> 4;
  const int d = blockIdx.x;
  const int bh = (d & 7) * 16 + ((d >> 3) & 15);
  const int q0 = (d >> 7) << 7;
  const int b = bh >> 4, h = bh & 15;

  half8 qf[2][2];
#pragma unroll
  for (int qs = 0; qs < 2; ++qs) {
    const _Float16* qp =
        qkv + (size_t)(b * 1024 + q0 + qs * 64 + w * 16 + l15) * 3072 + h * 64 + grp * 8;
    qf[qs][0] = *(const half8*)qp;
    qf[qs][1] = *(const half8*)(qp + 32);
  }
  half8 ones;
#pragma unroll
  for (int i = 0; i < 8; ++i) ones[i] = (_Float16)1.0f;

  f32x4 octx[2][4] = {};
  f32x4 lsum[2] = {};
  float mrun[2] = {-1e30f, -1e30f};

  for (int kt = 0; kt < 8; ++kt) {
    const int s0 = kt * 128;
#pragma unroll
    for (int i = 0; i < 4; ++i) {
      {
        int srow = i * 32 + (tid >> 3);
        int c8 = (tid & 7) ^ (srow & 7);
        glds16(qkv + (size_t)(b * 1024 + s0 + srow) * 3072 + 1024 + h * 64 + c8 * 8,
               Ks + w * 512 + i * 2048);
      }
      {
        int erow = i * 16 + (tid >> 4);
        int c16 = (tid & 15) ^ (erow & 7);
        glds16(Vt + (size_t)(bh * 64 + erow) * 1024 + s0 + c16 * 8,
               Vs + w * 512 + i * 2048);
      }
    }
    __syncthreads();
#pragma unroll
    for (int qs = 0; qs < 2; ++qs) {
      f32x4 sacc[8] = {};
      __builtin_amdgcn_s_setprio(1);
#pragma unroll
      for (int ks = 0; ks < 2; ++ks)
#pragma unroll
        for (int f = 0; f < 8; ++f) {
          int srow = f * 16 + l15;
          half8 kf = *(const half8*)&Ks[srow * 64 + ((ks * 32 + grp * 8) ^ ((srow & 7) * 8))];
          sacc[f] = __builtin_amdgcn_mfma_f32_16x16x32_f16(kf, qf[qs][ks], sacc[f], 0, 0, 0);
        }
      __builtin_amdgcn_s_setprio(0);
      float tmax = -1e30f;
#pragma unroll
      for (int f = 0; f < 8; ++f)
#pragma unroll
        for (int r = 0; r < 4; ++r) tmax = fmaxf(tmax, sacc[f][r]);
      tmax = fmaxf(tmax, __shfl_xor(tmax, 16));
      tmax = fmaxf(tmax, __shfl_xor(tmax, 32));
      if (!__all(tmax <= mrun[qs] + 8.0f)) {
        float mnew = fmaxf(mrun[qs], tmax);
        float corr = exp2f(mrun[qs] - mnew);
        mrun[qs] = mnew;
#pragma unroll
        for (int r = 0; r < 4; ++r) {
          float cq = __shfl(corr, (lane & 48) + grp * 4 + r);
#pragma unroll
          for (int jf = 0; jf < 4; ++jf) octx[qs][jf][r] *= cq;
          lsum[qs][r] *= cq;
        }
      }
#pragma unroll
      for (int f = 0; f < 8; ++f) {
        half4 pk;
#pragma unroll
        for (int r = 0; r < 4; ++r) pk[r] = (_Float16)exp2f(sacc[f][r] - mrun[qs]);
        *(half4*)&Ps[w][l15 * 136 + f * 16 + grp * 4] = pk;
      }
      __builtin_amdgcn_s_setprio(1);
#pragma unroll
      for (int ks2 = 0; ks2 < 4; ++ks2) {
        half8 pa = *(const half8*)&Ps[w][l15 * 136 + ks2 * 32 + grp * 8];
        lsum[qs] = __builtin_amdgcn_mfma_f32_16x16x32_f16(pa, ones, lsum[qs], 0, 0, 0);
#pragma unroll
        for (int jf = 0; jf < 4; ++jf) {
          int erow = jf * 16 + l15;
          half8 vb = *(const half8*)&Vs[erow * 128 + ((ks2 * 32 + grp * 8) ^ ((erow & 7) * 8))];
          octx[qs][jf] = __builtin_amdgcn_mfma_f32_16x16x32_f16(pa, vb, octx[qs][jf], 0, 0, 0);
        }
      }
      __builtin_amdgcn_s_setprio(0);
    }
    __syncthreads();
  }
#pragma unroll
  for (int qs = 0; qs < 2; ++qs) {
#pragma unroll
    for (int r = 0; r < 4; ++r) {
      float inv = 1.0f / lsum[qs][r];
      const size_t row = b * 1024 + q0 + qs * 64 + w * 16 + grp * 4 + r;
#pragma unroll
      for (int jf = 0; jf < 4; ++jf)
        ctx[row * 1024 + h * 64 + jf * 16 + l15] = (_Float16)(octx[qs][jf][r] * inv);
    }
  }
}

// ---------------- LayerNorm ----------------
__global__ __launch_bounds__(256) void k_ln(const float* xin, const float* __restrict__ gamma,
                                            const float* __restrict__ beta, float* out) {
  __shared__ float red[8];
  const int tid = threadIdx.x;
  const size_t row = blockIdx.x;
  f32x4 v = *(const f32x4*)&xin[row * 1024 + tid * 4];
  float s = v[0] + v[1] + v[2] + v[3];
  float s2 = v[0] * v[0] + v[1] * v[1] + v[2] * v[2] + v[3] * v[3];
#pragma unroll
  for (int o = 32; o >= 1; o >>= 1) {
    s += __shfl_xor(s, o);
    s2 += __shfl_xor(s2, o);
  }
  if ((tid & 63) == 0) { red[tid >> 6] = s; red[4 + (tid >> 6)] = s2; }
  __syncthreads();
  s = red[0] + red[1] + red[2] + red[3];
  s2 = red[4] + red[5] + red[6] + red[7];
  float mu = s * (1.0f / 1024.0f);
  float var = s2 * (1.0f / 1024.0f) - mu * mu;
  float rs = rsqrtf(var + 1e-5f);
  f32x4 g = *(const f32x4*)&gamma[tid * 4];
  f32x4 bt = *(const f32x4*)&beta[tid * 4];
  f32x4 o4;
#pragma unroll
  for (int r = 0; r < 4; ++r) o4[r] = (v[r] - mu) * rs * g[r] + bt[r];
  *(f32x4*)&out[row * 1024 + tid * 4] = o4;
}

extern "C" void kernel_launch(void* const* d_in, const int* in_sizes, int n_in,
                              void* d_out, int out_size, void* d_ws, size_t ws_size,
                              hipStream_t stream) {
  (void)in_sizes; (void)n_in; (void)out_size; (void)ws_size;
  const float* x  = (const float*)d_in[0];
  const float* Wq = (const float*)d_in[1];  const float* bq = (const float*)d_in[2];
  const float* Wk = (const float*)d_in[3];  const float* bk = (const float*)d_in[4];
  const float* Wv = (const float*)d_in[5];  const float* bv = (const float*)d_in[6];
  const float* Wo = (const float*)d_in[7];  const float* bo = (const float*)d_in[8];
  const float* W1 = (const float*)d_in[9];  const float* b1 = (const float*)d_in[10];
  const float* W2 = (const float*)d_in[11]; const float* b2 = (const float*)d_in[12];
  const float* gamma = (const float*)d_in[13];
  const float* beta  = (const float*)d_in[14];
  float* out = (float*)d_out;

  char* p = (char*)d_ws;
  _Float16* xb    = (_Float16*)p;  p += (size_t)16 << 20;   // x f16 (NOT reused)
  _Float16* qkv   = (_Float16*)p;
  _Float16* hbuf  = (_Float16*)p;  p += (size_t)48 << 20;   // qkv; reused as h after attn
  _Float16* Vt    = (_Float16*)p;  p += (size_t)16 << 20;
  _Float16* ctx   = (_Float16*)p;  p += (size_t)16 << 20;   // dedicated ctx buffer
  _Float16* Wqkvt = (_Float16*)p;  p += (size_t)3072 * 1024 * 2;
  _Float16* Wot   = (_Float16*)p;  p += (size_t)1024 * 1024 * 2;
  _Float16* W1t   = (_Float16*)p;  p += (size_t)4096 * 1024 * 2;
  _Float16* W2t   = (_Float16*)p;  p += (size_t)4096 * 1024 * 2;
  float*    bqkv  = (float*)p;     p += (size_t)3072 * 4;
  _Float16* x1b   = (_Float16*)p;  p += (size_t)16 << 20;

  // fused prep: cvt (4096) + transposes (3072) + biascat (12) = 7180 blocks
  k_prep<<<7180, 256, 0, stream>>>(x, xb, Wq, Wk, Wv, Wo, W1, W2,
                                   Wqkvt, Wot, W1t, W2t, bq, bk, bv, bqkv);

  // QKV: fat128 + fused V-transpose + Q-prescale -> 24x32 = 768 blocks
  k_gemmf<5><<<dim3(24, 32), 512, 0, stream>>>(xb, Wqkvt, bqkv, nullptr, (float*)Vt, qkv,
                                               8192, 3072, 1024);
  // attention: XCD-local 1-D grid, KV-tile 128, 2 Q-tiles/block -> 1024 blocks
  k_attn<<<1024, 256, 0, stream>>>(qkv, Vt, ctx);
  // x1b = (f16)(xb + ctx@Wo + bo) : fat128 -> 8x32 = 256 blocks
  k_gemmf<1><<<dim3(8, 32), 512, 0, stream>>>(ctx, Wot, bo, xb, nullptr, x1b,
                                              8192, 1024, 1024);
  // h = gelu(x1b@W1 + b1) : quadrant + deep spread staging -> 16x32 = 512 blocks
  k_gemm8<256, 2><<<dim3(16, 32), 512, 0, stream>>>(x1b, W1t, b1, nullptr, nullptr, hbuf,
                                                    8192, 4096, 1024);
  // out = x1b + h@W2 + b2 (f32) : fat128, K=4096 -> 8x32 = 256 blocks
  k_gemmf<4><<<dim3(8, 32), 512, 0, stream>>>(hbuf, W2t, b2, x1b, out, nullptr,
                                              8192, 1024, 4096);
  k_ln<<<8192, 256, 0, stream>>>(out, gamma, beta, out);
}

// Round 18
// 330.721 us; speedup vs baseline: 1.0387x; 1.0034x over previous
//
#include <hip/hip_runtime.h>
#include <cmath>

typedef __attribute__((ext_vector_type(8))) _Float16 half8;
typedef __attribute__((ext_vector_type(4))) _Float16 half4;
typedef __attribute__((ext_vector_type(4))) float f32x4;

__device__ __forceinline__ void glds16(const void* g, void* l) {
  __builtin_amdgcn_global_load_lds(
      (__attribute__((address_space(1))) const void*)g,
      (__attribute__((address_space(3))) void*)l, 16, 0, 0);
}

// A&S 7.1.26, |err| <= 1.5e-7
__device__ __forceinline__ float fast_erf(float x) {
  float ax = fabsf(x);
  float t = 1.0f / (1.0f + 0.3275911f * ax);
  float y = t * (0.254829592f +
            t * (-0.284496736f +
            t * (1.421413741f +
            t * (-1.453152027f + t * 1.061405429f))));
  float r = 1.0f - y * __expf(-ax * ax);
  return copysignf(r, x);
}

// ======== fused prep: x cvt (4096 blk) + 6 weight transposes (3072 blk) + biascat (12 blk) ========
__global__ __launch_bounds__(256) void k_prep(
    const float* __restrict__ x, _Float16* __restrict__ xb,
    const float* __restrict__ Wq, const float* __restrict__ Wk,
    const float* __restrict__ Wv, const float* __restrict__ Wo,
    const float* __restrict__ W1, const float* __restrict__ W2,
    _Float16* __restrict__ Wqkvt, _Float16* __restrict__ Wot,
    _Float16* __restrict__ W1t, _Float16* __restrict__ W2t,
    const float* __restrict__ bq, const float* __restrict__ bk,
    const float* __restrict__ bv, float* __restrict__ bqkv) {
  __shared__ float t[64][65];
  const int tid = threadIdx.x;
  const int bid = blockIdx.x;
  if (bid < 4096) {  // x f32 -> f16
    int i = (bid * 256 + tid) * 8;
    const f32x4* p = (const f32x4*)(x + i);
    f32x4 a = p[0], b = p[1];
    half8 h;
    h[0] = (_Float16)a[0]; h[1] = (_Float16)a[1]; h[2] = (_Float16)a[2]; h[3] = (_Float16)a[3];
    h[4] = (_Float16)b[0]; h[5] = (_Float16)b[1]; h[6] = (_Float16)b[2]; h[7] = (_Float16)b[3];
    *(half8*)(xb + i) = h;
    return;
  }
  const int tt = bid - 4096;
  if (tt >= 3072) {  // biascat (12 blocks)
    int i = (tt - 3072) * 256 + tid;
    const float* s = i < 1024 ? bq : (i < 2048 ? bk : bv);
    bqkv[i] = s[i & 1023];
    return;
  }
  // weight transpose: W [K,N] f32 -> Wt [N,K] f16, 64x64 tile
  const float* W; _Float16* Wt; int K, N, bx, by;
  if (tt < 1024) {
    const int wsel = tt >> 8, r = tt & 255;
    W = wsel == 0 ? Wq : wsel == 1 ? Wk : wsel == 2 ? Wv : Wo;
    Wt = wsel < 3 ? Wqkvt + (size_t)wsel * 1024 * 1024 : Wot;
    K = 1024; N = 1024; bx = r & 15; by = r >> 4;
  } else if (tt < 2048) {
    const int r = tt - 1024;
    W = W1; Wt = W1t; K = 1024; N = 4096; bx = r & 63; by = r >> 6;
  } else {
    const int r = tt - 2048;
    W = W2; Wt = W2t; K = 4096; N = 1024; bx = r & 15; by = r >> 4;
  }
  const int k0 = by << 6, n0 = bx << 6;
  {
    const int r = tid >> 2, q = tid & 3;
    const float* src = &W[(size_t)(k0 + r) * N + n0 + q * 16];
    f32x4 v0 = *(const f32x4*)(src);
    f32x4 v1 = *(const f32x4*)(src + 4);
    f32x4 v2 = *(const f32x4*)(src + 8);
    f32x4 v3 = *(const f32x4*)(src + 12);
    float* d = &t[r][q * 16];
#pragma unroll
    for (int j = 0; j < 4; ++j) d[j] = v0[j];
#pragma unroll
    for (int j = 0; j < 4; ++j) d[4 + j] = v1[j];
#pragma unroll
    for (int j = 0; j < 4; ++j) d[8 + j] = v2[j];
#pragma unroll
    for (int j = 0; j < 4; ++j) d[12 + j] = v3[j];
  }
  __syncthreads();
#pragma unroll
  for (int p = 0; p < 2; ++p) {
    const int c = p * 256 + tid;
    const int row = c >> 3, c8 = c & 7;
    half8 hv;
#pragma unroll
    for (int j = 0; j < 8; ++j) hv[j] = (_Float16)t[c8 * 8 + j][row];
    *(half8*)&Wt[(size_t)(n0 + row) * K + k0 + c8 * 8] = hv;
  }
}

// ======== quadrant 8-phase GEMM: BM=256,BN=256, BK=64, dbuf, DEEP spread staging ========
template <int BM, int EPI>
__global__ __launch_bounds__(512, 2) void k_gemm8(
    const _Float16* __restrict__ A, const _Float16* __restrict__ Bt,
    const float* __restrict__ bias, const float* __restrict__ res,
    float* __restrict__ outf, _Float16* __restrict__ outh, int M, int N, int K) {
  constexpr int MR = BM / 32;
  constexpr int MH2 = MR / 2;
  constexpr int AL = BM * 64;
  constexpr int BL = 256 * 64;
  constexpr int ABYTES = BM * 128;
  constexpr int BBYTES = 256 * 128;
  constexpr int AB2 = 2 * ABYTES;
  __shared__ _Float16 lds[2 * (AL + BL)];
  const char* ldsc = (const char*)lds;

  const int tid = threadIdx.x;
  const int lane = tid & 63;
  const int w = tid >> 6, wr = w >> 2, wc = w & 3;
  const int l15 = lane & 15, grp = lane >> 4;

  const int gx = gridDim.x;
  const int nwg = gx * gridDim.y;
  const int lid = blockIdx.y * gx + blockIdx.x;
  const int wid = (lid & 7) * (nwg >> 3) + (lid >> 3);
  const int m0 = (wid / gx) * BM, n0 = (wid % gx) * 256;

  const int m2 = (l15 >> 2) & 1, m01 = l15 & 3;
  const int chunk0 = (m2 << 2) | (grp ^ m01);
  const int aoff0 = wr * 2048 + l15 * 128 + chunk0 * 16;
  const int aoff1 = aoff0 ^ 64;
  const int boff0 = wc * 2048 + l15 * 128 + chunk0 * 16;
  const int boff1 = boff0 ^ 64;

  const int srow = tid >> 3;
  const int scs8 = ((tid & 7) ^ (srow & 7)) * 8;
  const int NK = K >> 6;

  f32x4 acc[MR][4] = {};
  half8 af[MH2][2], bf[2][2];

#define STG_A(J, MHH, KN)                                                      \
  _Pragma("unroll") for (int s = 0; s < BM / 128; ++s)                         \
      glds16(A + (size_t)(m0 + (MHH) * (BM / 2) + s * 64 + srow) * K +         \
                 (size_t)(KN)*64 + scs8,                                       \
             lds + (J)*AL + ((MHH) * (BM / 2) + s * 64) * 64 + tid * 8);
#define STG_B(J, NHH, KN)                                                      \
  _Pragma("unroll") for (int s = 0; s < 2; ++s)                                \
      glds16(Bt + (size_t)(n0 + (NHH)*128 + s * 64 + srow) * K +               \
                  (size_t)(KN)*64 + scs8,                                      \
             lds + 2 * AL + (J)*BL + ((NHH)*128 + s * 64) * 64 + tid * 8);

#define VM_8 asm volatile("s_waitcnt vmcnt(8)" ::: "memory")
#define VM_6 asm volatile("s_waitcnt vmcnt(6)" ::: "memory")
#define VM_NONE

#define PHASE(J, MHQ, NHQ, RA, RB, STGSTMT, VMSTMT)                            \
  {                                                                            \
    if constexpr (RA) {                                                        \
      _Pragma("unroll") for (int i = 0; i < MH2; ++i) {                        \
        af[i][0] = *(const half8*)(ldsc + (J)*ABYTES +                         \
                                   ((MHQ)*MH2 + i) * 4096 + aoff0);            \
        af[i][1] = *(const half8*)(ldsc + (J)*ABYTES +                         \
                                   ((MHQ)*MH2 + i) * 4096 + aoff1);            \
      }                                                                        \
    }                                                                          \
    if constexpr (RB) {                                                        \
      _Pragma("unroll") for (int n = 0; n < 2; ++n) {                          \
        bf[n][0] = *(const half8*)(ldsc + AB2 + (J)*BBYTES +                   \
                                   ((NHQ)*2 + n) * 8192 + boff0);              \
        bf[n][1] = *(const half8*)(ldsc + AB2 + (J)*BBYTES +                   \
                                   ((NHQ)*2 + n) * 8192 + boff1);              \
      }                                                                        \
    }                                                                          \
    STGSTMT;                                                                   \
    __builtin_amdgcn_s_barrier();                                              \
    asm volatile("s_waitcnt lgkmcnt(0)");                                      \
    __builtin_amdgcn_sched_barrier(0);                                         \
    __builtin_amdgcn_s_setprio(1);                                             \
    _Pragma("unroll") for (int ks = 0; ks < 2; ++ks)                           \
        _Pragma("unroll") for (int i = 0; i < MH2; ++i)                        \
            _Pragma("unroll") for (int n = 0; n < 2; ++n)                      \
                acc[(MHQ)*MH2 + i][(NHQ)*2 + n] =                              \
                    __builtin_amdgcn_mfma_f32_16x16x32_f16(                    \
                        af[i][ks], bf[n][ks], acc[(MHQ)*MH2 + i][(NHQ)*2 + n], \
                        0, 0, 0);                                              \
    __builtin_amdgcn_s_setprio(0);                                             \
    VMSTMT;                                                                    \
    __builtin_amdgcn_s_barrier();                                              \
  }

#define KTILE(J, KT)                                                           \
  {                                                                            \
    const int kn1_ = ((KT) + 1 < NK) ? (KT) + 1 : NK - 1;                      \
    const int kn2_ = ((KT) + 2 < NK) ? (KT) + 2 : NK - 1;                      \
    PHASE(J, 0, 0, true, true, STG_B(1 - (J), 0, kn1_), VM_NONE)               \
    PHASE(J, 0, 1, false, true, STG_A(1 - (J), 1, kn1_), VM_8)                 \
    PHASE(J, 1, 1, true, false, STG_A(J, 0, kn2_), VM_NONE)                    \
    PHASE(J, 1, 0, false, true, STG_B(J, 1, kn2_), VM_6)                       \
  }

  STG_A(0, 0, 0) STG_B(0, 0, 0) STG_B(0, 1, 0) STG_A(0, 1, 0)
  STG_A(1, 0, 1) STG_B(1, 1, 1)
  VM_6;
  __builtin_amdgcn_s_barrier();

#pragma unroll 1
  for (int kt = 0; kt < NK; kt += 2) {
    KTILE(0, kt)
    KTILE(1, kt + 1)
  }
  asm volatile("s_waitcnt vmcnt(0)" ::: "memory");
#undef KTILE
#undef PHASE
#undef VM_8
#undef VM_6
#undef VM_NONE
#undef STG_A
#undef STG_B

  float bcol[4];
#pragma unroll
  for (int n = 0; n < 4; ++n) bcol[n] = bias[n0 + (n * 4 + wc) * 16 + l15];
#pragma unroll
  for (int m = 0; m < MR; ++m) {
#pragma unroll
    for (int rr = 0; rr < 4; ++rr) {
      const size_t row = m0 + (m * 2 + wr) * 16 + grp * 4 + rr;
#pragma unroll
      for (int n = 0; n < 4; ++n) {
        const int col = n0 + (n * 4 + wc) * 16 + l15;
        float v = acc[m][n][rr] + bcol[n];
        const size_t idx = row * N + col;
        if (EPI == 0) {
          outh[idx] = (_Float16)v;
        } else if (EPI == 1) {
          float t2 = v + res[idx];
          outf[idx] = t2;
          outh[idx] = (_Float16)t2;
        } else if (EPI == 2) {
          float g = 0.5f * v * (1.0f + fast_erf(v * 0.70710678118654752f));
          outh[idx] = (_Float16)g;
        } else {
          outf[idx] = v + res[idx];
        }
      }
    }
  }
}

// ======== fat-phase tri-buffer GEMM: BM=256, BN=128, BK=64, 2 phases/K-tile ========
// EPI 0: outh=(f16)(acc+bias); 1: outh=(f16)(acc+bias+(float)res_f16);
// EPI 2: outh=(f16)gelu(acc+bias); 4: outf=acc+bias+(float)res_f16;
// EPI 5 (QKV): col<1024 -> Q scaled by 0.125*log2e; col<2048 -> qkv; else Vt (half4).
template <int EPI>
__global__ __launch_bounds__(512, 2) void k_gemmf(
    const _Float16* __restrict__ A, const _Float16* __restrict__ Bt,
    const float* __restrict__ bias, const void* __restrict__ res,
    float* __restrict__ outf, _Float16* __restrict__ outh, int M, int N, int K) {
  constexpr int AL = 256 * 64, BL = 128 * 64;
  constexpr int ABY = 32768, BBY = 16384, BBASE = 3 * ABY;
  __shared__ _Float16 lds[3 * (AL + BL)];
  const char* ldsc = (const char*)lds;

  const int tid = threadIdx.x;
  const int lane = tid & 63;
  const int w = tid >> 6, wr = w >> 1, wc = w & 1;
  const int l15 = lane & 15, grp = lane >> 4;

  const int gx = gridDim.x;
  const int nwg = gx * gridDim.y;
  const int lid = blockIdx.y * gx + blockIdx.x;
  const int wid = (lid & 7) * (nwg >> 3) + (lid >> 3);
  const int m0 = (wid / gx) * 256, n0 = (wid % gx) * 128;

  const int m2 = (l15 >> 2) & 1, m01 = l15 & 3;
  const int c0 = ((m2 << 2) | (grp ^ m01)) * 16;
  const int aoff0 = wr * 2048 + l15 * 128 + c0;
  const int aoff1 = aoff0 ^ 64;
  const int boff0 = wc * 2048 + l15 * 128 + c0;
  const int boff1 = boff0 ^ 64;

  const int srow = tid >> 3;
  const int scs8 = ((tid & 7) ^ (srow & 7)) * 8;
  const int NK = K >> 6;

  const _Float16* aG = A + (size_t)(m0 + srow) * K + scs8;
  const _Float16* bG = Bt + (size_t)(n0 + srow) * K + scs8;

  f32x4 acc[4][4] = {};

#define FSTG_A(JJ, HH, KN)                                                     \
  _Pragma("unroll") for (int s = 0; s < 2; ++s)                                \
      glds16(aG + (size_t)((HH)*128 + s * 64) * K + (size_t)(KN)*64,           \
             lds + (JJ)*AL + ((HH)*128 + s * 64) * 64 + tid * 8);
#define FSTG_B(JJ, HH, KN)                                                     \
  glds16(bG + (size_t)((HH)*64) * K + (size_t)(KN)*64,                         \
         lds + 3 * AL + (JJ)*BL + (HH)*64 * 64 + tid * 8);

#define FPHASE(PA, PB, AO, BO, STGSTMT, VMSTMT)                                \
  {                                                                            \
    half8 af_[4], bf_[4];                                                      \
    _Pragma("unroll") for (int m = 0; m < 4; ++m)                              \
        af_[m] = *(const half8*)((PA) + m * 8192 + (AO));                      \
    _Pragma("unroll") for (int n = 0; n < 4; ++n)                              \
        bf_[n] = *(const half8*)((PB) + n * 4096 + (BO));                      \
    STGSTMT;                                                                   \
    __builtin_amdgcn_s_barrier();                                              \
    asm volatile("s_waitcnt lgkmcnt(0)");                                      \
    __builtin_amdgcn_sched_barrier(0);                                         \
    __builtin_amdgcn_s_setprio(1);                                             \
    _Pragma("unroll") for (int m = 0; m < 4; ++m)                              \
        _Pragma("unroll") for (int n = 0; n < 4; ++n)                          \
            acc[m][n] = __builtin_amdgcn_mfma_f32_16x16x32_f16(                \
                af_[m], bf_[n], acc[m][n], 0, 0, 0);                           \
    __builtin_amdgcn_s_setprio(0);                                             \
    VMSTMT;                                                                    \
    __builtin_amdgcn_s_barrier();                                              \
  }

  FSTG_A(0, 0, 0) FSTG_A(0, 1, 0) FSTG_B(0, 0, 0) FSTG_B(0, 1, 0)
  FSTG_A(1, 0, 1) FSTG_A(1, 1, 1) FSTG_B(1, 0, 1) FSTG_B(1, 1, 1)
  asm volatile("s_waitcnt vmcnt(6)" ::: "memory");
  __builtin_amdgcn_s_barrier();

  int j = 0, j2 = 2;
#pragma unroll 1
  for (int kt = 0; kt < NK; ++kt) {
    const int kn = (kt + 2 < NK) ? kt + 2 : NK - 1;
    const char* pa = ldsc + j * ABY;
    const char* pb = ldsc + BBASE + j * BBY;
    FPHASE(pa, pb, aoff0, boff0, { FSTG_A(j2, 0, kn) FSTG_B(j2, 0, kn) }, )
    FPHASE(pa, pb, aoff1, boff1, { FSTG_A(j2, 1, kn) FSTG_B(j2, 1, kn) },
           asm volatile("s_waitcnt vmcnt(6)" ::: "memory");)
    j = (j == 2) ? 0 : j + 1;
    j2 = (j2 == 2) ? 0 : j2 + 1;
  }
  asm volatile("s_waitcnt vmcnt(0)" ::: "memory");
#undef FPHASE
#undef FSTG_A
#undef FSTG_B

  float bcol[4];
#pragma unroll
  for (int n = 0; n < 4; ++n) bcol[n] = bias[n0 + (n * 2 + wc) * 16 + l15];
  if (EPI == 5) {
    const float QSC = 0.125f * 1.44269504088896f;
    _Float16* vt = (_Float16*)outf;
#pragma unroll
    for (int m = 0; m < 4; ++m) {
#pragma unroll
      for (int n = 0; n < 4; ++n) {
        const int col = n0 + (n * 2 + wc) * 16 + l15;
        const size_t row0 = m0 + (m * 4 + wr) * 16 + grp * 4;
        if (col < 2048) {
          const float scl = (col < 1024) ? QSC : 1.0f;
#pragma unroll
          for (int rr = 0; rr < 4; ++rr)
            outh[(row0 + rr) * (size_t)N + col] = (_Float16)((acc[m][n][rr] + bcol[n]) * scl);
        } else {
          const int b = (int)(row0 >> 10), s = (int)(row0 & 1023);
          const int cv = col - 2048, hh = cv >> 6, e = cv & 63;
          half4 pk;
#pragma unroll
          for (int rr = 0; rr < 4; ++rr) pk[rr] = (_Float16)(acc[m][n][rr] + bcol[n]);
          *(half4*)&vt[((size_t)((b << 4) | hh) * 64 + e) * 1024 + s] = pk;
        }
      }
    }
    return;
  }
#pragma unroll
  for (int m = 0; m < 4; ++m) {
#pragma unroll
    for (int rr = 0; rr < 4; ++rr) {
      const size_t row = m0 + (m * 4 + wr) * 16 + grp * 4 + rr;
#pragma unroll
      for (int n = 0; n < 4; ++n) {
        const int col = n0 + (n * 2 + wc) * 16 + l15;
        float v = acc[m][n][rr] + bcol[n];
        const size_t idx = row * N + col;
        if (EPI == 0) {
          outh[idx] = (_Float16)v;
        } else if (EPI == 1) {
          float t2 = v + (float)((const _Float16*)res)[idx];
          outh[idx] = (_Float16)t2;
        } else if (EPI == 2) {
          float g = 0.5f * v * (1.0f + fast_erf(v * 0.70710678118654752f));
          outh[idx] = (_Float16)g;
        } else {
          float t2 = v + (float)((const _Float16*)res)[idx];
          outf[idx] = t2;
        }
      }
    }
  }
}

// ---- flash attention (r14-measured version): 4 waves, 2 Q-tiles/block, KV-tile 128 ----
__global__ __launch_bounds__(256) void k_attn(const _Float16* __restrict__ qkv,
                                              const _Float16* __restrict__ Vt,
                                              _Float16* __restrict__ ctx) {
  __shared__ _Float16 Ks[128 * 64];
  __shared__ _Float16 Vs[64 * 128];
  __shared__ _Float16 Ps[4][16 * 136];
  const int tid = threadIdx.x;
  const int lane = tid & 63, w = tid >> 6;
  const int l15 = lane & 15, grp = lane >> 4;
  const int d = blockIdx.x;
  const int bh = (d & 7) * 16 + ((d >> 3) & 15);
  const int q0 = (d >> 7) << 7;
  const int b = bh >> 4, h = bh & 15;

  half8 qf[2][2];
#pragma unroll
  for (int qs = 0; qs < 2; ++qs) {
    const _Float16* qp =
        qkv + (size_t)(b * 1024 + q0 + qs * 64 + w * 16 + l15) * 3072 + h * 64 + grp * 8;
    qf[qs][0] = *(const half8*)qp;
    qf[qs][1] = *(const half8*)(qp + 32);
  }
  half8 ones;
#pragma unroll
  for (int i = 0; i < 8; ++i) ones[i] = (_Float16)1.0f;

  f32x4 octx[2][4] = {};
  f32x4 lsum[2] = {};
  float mrun[2] = {-1e30f, -1e30f};

  for (int kt = 0; kt < 8; ++kt) {
    const int s0 = kt * 128;
#pragma unroll
    for (int i = 0; i < 4; ++i) {
      {
        int srow = i * 32 + (tid >> 3);
        int c8 = (tid & 7) ^ (srow & 7);
        glds16(qkv + (size_t)(b * 1024 + s0 + srow) * 3072 + 1024 + h * 64 + c8 * 8,
               Ks + w * 512 + i * 2048);
      }
      {
        int erow = i * 16 + (tid >> 4);
        int c16 = (tid & 15) ^ (erow & 7);
        glds16(Vt + (size_t)(bh * 64 + erow) * 1024 + s0 + c16 * 8,
               Vs + w * 512 + i * 2048);
      }
    }
    __syncthreads();
#pragma unroll
    for (int qs = 0; qs < 2; ++qs) {
      f32x4 sacc[8] = {};
      __builtin_amdgcn_s_setprio(1);
#pragma unroll
      for (int ks = 0; ks < 2; ++ks)
#pragma unroll
        for (int f = 0; f < 8; ++f) {
          int srow = f * 16 + l15;
          half8 kf = *(const half8*)&Ks[srow * 64 + ((ks * 32 + grp * 8) ^ ((srow & 7) * 8))];
          sacc[f] = __builtin_amdgcn_mfma_f32_16x16x32_f16(kf, qf[qs][ks], sacc[f], 0, 0, 0);
        }
      __builtin_amdgcn_s_setprio(0);
      float tmax = -1e30f;
#pragma unroll
      for (int f = 0; f < 8; ++f)
#pragma unroll
        for (int r = 0; r < 4; ++r) tmax = fmaxf(tmax, sacc[f][r]);
      tmax = fmaxf(tmax, __shfl_xor(tmax, 16));
      tmax = fmaxf(tmax, __shfl_xor(tmax, 32));
      if (!__all(tmax <= mrun[qs] + 8.0f)) {
        float mnew = fmaxf(mrun[qs], tmax);
        float corr = exp2f(mrun[qs] - mnew);
        mrun[qs] = mnew;
#pragma unroll
        for (int r = 0; r < 4; ++r) {
          float cq = __shfl(corr, (lane & 48) + grp * 4 + r);
#pragma unroll
          for (int jf = 0; jf < 4; ++jf) octx[qs][jf][r] *= cq;
          lsum[qs][r] *= cq;
        }
      }
#pragma unroll
      for (int f = 0; f < 8; ++f) {
        half4 pk;
#pragma unroll
        for (int r = 0; r < 4; ++r) pk[r] = (_Float16)exp2f(sacc[f][r] - mrun[qs]);
        *(half4*)&Ps[w][l15 * 136 + f * 16 + grp * 4] = pk;
      }
      __builtin_amdgcn_s_setprio(1);
#pragma unroll
      for (int ks2 = 0; ks2 < 4; ++ks2) {
        half8 pa = *(const half8*)&Ps[w][l15 * 136 + ks2 * 32 + grp * 8];
        lsum[qs] = __builtin_amdgcn_mfma_f32_16x16x32_f16(pa, ones, lsum[qs], 0, 0, 0);
#pragma unroll
        for (int jf = 0; jf < 4; ++jf) {
          int erow = jf * 16 + l15;
          half8 vb = *(const half8*)&Vs[erow * 128 + ((ks2 * 32 + grp * 8) ^ ((erow & 7) * 8))];
          octx[qs][jf] = __builtin_amdgcn_mfma_f32_16x16x32_f16(pa, vb, octx[qs][jf], 0, 0, 0);
        }
      }
      __builtin_amdgcn_s_setprio(0);
    }
    __syncthreads();
  }
#pragma unroll
  for (int qs = 0; qs < 2; ++qs) {
#pragma unroll
    for (int r = 0; r < 4; ++r) {
      float inv = 1.0f / lsum[qs][r];
      const size_t row = b * 1024 + q0 + qs * 64 + w * 16 + grp * 4 + r;
#pragma unroll
      for (int jf = 0; jf < 4; ++jf)
        ctx[row * 1024 + h * 64 + jf * 16 + l15] = (_Float16)(octx[qs][jf][r] * inv);
    }
  }
}

// ---------------- LayerNorm from f16 input -> f32 out ----------------
__global__ __launch_bounds__(256) void k_ln_h(const _Float16* __restrict__ xin,
                                              const float* __restrict__ gamma,
                                              const float* __restrict__ beta,
                                              float* __restrict__ out) {
  __shared__ float red[8];
  const int tid = threadIdx.x;
  const size_t row = blockIdx.x;
  half4 h4 = *(const half4*)&xin[row * 1024 + tid * 4];
  f32x4 v;
#pragma unroll
  for (int r = 0; r < 4; ++r) v[r] = (float)h4[r];
  float s = v[0] + v[1] + v[2] + v[3];
  float s2 = v[0] * v[0] + v[1] * v[1] + v[2] * v[2] + v[3] * v[3];
#pragma unroll
  for (int o = 32; o >= 1; o >>= 1) {
    s += __shfl_xor(s, o);
    s2 += __shfl_xor(s2, o);
  }
  if ((tid & 63) == 0) { red[tid >> 6] = s; red[4 + (tid >> 6)] = s2; }
  __syncthreads();
  s = red[0] + red[1] + red[2] + red[3];
  s2 = red[4] + red[5] + red[6] + red[7];
  float mu = s * (1.0f / 1024.0f);
  float var = s2 * (1.0f / 1024.0f) - mu * mu;
  float rs = rsqrtf(var + 1e-5f);
  f32x4 g = *(const f32x4*)&gamma[tid * 4];
  f32x4 bt = *(const f32x4*)&beta[tid * 4];
  f32x4 o4;
#pragma unroll
  for (int r = 0; r < 4; ++r) o4[r] = (v[r] - mu) * rs * g[r] + bt[r];
  *(f32x4*)&out[row * 1024 + tid * 4] = o4;
}

extern "C" void kernel_launch(void* const* d_in, const int* in_sizes, int n_in,
                              void* d_out, int out_size, void* d_ws, size_t ws_size,
                              hipStream_t stream) {
  (void)in_sizes; (void)n_in; (void)out_size; (void)ws_size;
  const float* x  = (const float*)d_in[0];
  const float* Wq = (const float*)d_in[1];  const float* bq = (const float*)d_in[2];
  const float* Wk = (const float*)d_in[3];  const float* bk = (const float*)d_in[4];
  const float* Wv = (const float*)d_in[5];  const float* bv = (const float*)d_in[6];
  const float* Wo = (const float*)d_in[7];  const float* bo = (const float*)d_in[8];
  const float* W1 = (const float*)d_in[9];  const float* b1 = (const float*)d_in[10];
  const float* W2 = (const float*)d_in[11]; const float* b2 = (const float*)d_in[12];
  const float* gamma = (const float*)d_in[13];
  const float* beta  = (const float*)d_in[14];
  float* out = (float*)d_out;

  char* p = (char*)d_ws;
  _Float16* xb    = (_Float16*)p;  p += (size_t)16 << 20;   // x f16 (NOT reused)
  _Float16* qkv   = (_Float16*)p;
  _Float16* hbuf  = (_Float16*)p;  p += (size_t)48 << 20;   // qkv; reused as h after attn
  _Float16* Vt    = (_Float16*)p;  p += (size_t)16 << 20;
  _Float16* ctx   = (_Float16*)p;  p += (size_t)16 << 20;   // dedicated ctx buffer
  _Float16* Wqkvt = (_Float16*)p;  p += (size_t)3072 * 1024 * 2;
  _Float16* Wot   = (_Float16*)p;  p += (size_t)1024 * 1024 * 2;
  _Float16* W1t   = (_Float16*)p;  p += (size_t)4096 * 1024 * 2;
  _Float16* W2t   = (_Float16*)p;  p += (size_t)4096 * 1024 * 2;
  float*    bqkv  = (float*)p;     p += (size_t)3072 * 4;
  _Float16* x1b   = (_Float16*)p;  p += (size_t)16 << 20;
  _Float16* x2b   = (_Float16*)p;  p += (size_t)16 << 20;

  // fused prep: cvt (4096) + transposes (3072) + biascat (12) = 7180 blocks
  k_prep<<<7180, 256, 0, stream>>>(x, xb, Wq, Wk, Wv, Wo, W1, W2,
                                   Wqkvt, Wot, W1t, W2t, bq, bk, bv, bqkv);

  // QKV: fat128 + fused V-transpose + Q-prescale -> 24x32 = 768 blocks
  k_gemmf<5><<<dim3(24, 32), 512, 0, stream>>>(xb, Wqkvt, bqkv, nullptr, (float*)Vt, qkv,
                                               8192, 3072, 1024);
  // attention: XCD-local 1-D grid, KV-tile 128, 2 Q-tiles/block -> 1024 blocks
  k_attn<<<1024, 256, 0, stream>>>(qkv, Vt, ctx);
  // x1b = (f16)(xb + ctx@Wo + bo) : fat128 -> 8x32 = 256 blocks
  k_gemmf<1><<<dim3(8, 32), 512, 0, stream>>>(ctx, Wot, bo, xb, nullptr, x1b,
                                              8192, 1024, 1024);
  // h = gelu(x1b@W1 + b1) : quadrant + deep spread staging -> 16x32 = 512 blocks
  k_gemm8<256, 2><<<dim3(16, 32), 512, 0, stream>>>(x1b, W1t, b1, nullptr, nullptr, hbuf,
                                                    8192, 4096, 1024);
  // x2b = (f16)(x1b + h@W2 + b2) : fat128, K=4096 -> 8x32 = 256 blocks
  k_gemmf<1><<<dim3(8, 32), 512, 0, stream>>>(hbuf, W2t, b2, x1b, nullptr, x2b,
                                              8192, 1024, 4096);
  // LayerNorm from f16 -> f32 d_out
  k_ln_h<<<8192, 256, 0, stream>>>(x2b, gamma, beta, out);
}